// Round 4
// baseline (867.246 us; speedup 1.0000x reference)
//
#include <hip/hip_runtime.h>
#include <hip/hip_bf16.h>

// GCN->BiLSTM classifier on MI355X — R4.
// R3 post-mortem: K2 at 1 block/CU exposed every barrier drain + load
// latency (7100 cyc/iter vs 2100 LDS-bound floor). R4: single-buffered A
// (dbuf B only) -> 65 KB LDS -> 2 blocks/CU; truncation-based bf16 split
// (half the VALU); A global loads issued after compute (VGPR<=128, no
// spill at 16 waves/CU); 512-block grids via split-K 8 (K2).
// Precision: 3-product split bf16 (Ah*Bh + Ah*Bl + Al*Bh), err ~2^-16 rel.

typedef float f32x4 __attribute__((ext_vector_type(4)));
typedef __bf16 bf16x8 __attribute__((ext_vector_type(8)));
typedef unsigned short u16;
typedef unsigned int u32;

__device__ __forceinline__ u16 bf_hi_rn(float x, float& rem) {
    u32 u = __builtin_bit_cast(u32, x);
    u32 r = u + 0x7FFFu + ((u >> 16) & 1u);
    u16 h = (u16)(r >> 16);
    float hf = __builtin_bit_cast(float, (u32)h << 16);
    rem = x - hf;
    return h;
}
__device__ __forceinline__ u16 bf_trunc(float x) {
    return (u16)(__builtin_bit_cast(u32, x) >> 16);
}
// round-to-nearest pack (weights / splitout epilogue — off the hot loop)
__device__ __forceinline__ void pack8(const float* v, uint4& H, uint4& L) {
    u32 h[4], l[4];
#pragma unroll
    for (int q = 0; q < 4; q++) {
        float r0, r1;
        u32 h0 = bf_hi_rn(v[2 * q], r0);
        u32 h1 = bf_hi_rn(v[2 * q + 1], r1);
        h[q] = h0 | (h1 << 16);
        l[q] = (u32)bf_trunc(r0) | ((u32)bf_trunc(r1) << 16);
    }
    H = make_uint4(h[0], h[1], h[2], h[3]);
    L = make_uint4(l[0], l[1], l[2], l[3]);
}
// truncation pack (hot loop: ~5 VALU/elem)
__device__ __forceinline__ void pack8t(const float* v, uint4& H, uint4& L) {
    u32 h[4], l[4];
#pragma unroll
    for (int q = 0; q < 4; q++) {
        u32 u0 = __builtin_bit_cast(u32, v[2 * q]);
        u32 u1 = __builtin_bit_cast(u32, v[2 * q + 1]);
        h[q] = (u0 >> 16) | (u1 & 0xFFFF0000u);
        float r0 = v[2 * q] - __builtin_bit_cast(float, u0 & 0xFFFF0000u);
        float r1 = v[2 * q + 1] - __builtin_bit_cast(float, u1 & 0xFFFF0000u);
        l[q] = (__builtin_bit_cast(u32, r0) >> 16) |
               (__builtin_bit_cast(u32, r1) & 0xFFFF0000u);
    }
    H = make_uint4(h[0], h[1], h[2], h[3]);
    L = make_uint4(l[0], l[1], l[2], l[3]);
}

__device__ __forceinline__ void glds16(const u16* g, u16* l) {
    __builtin_amdgcn_global_load_lds(
        (const __attribute__((address_space(1))) void*)g,
        (__attribute__((address_space(3))) void*)l, 16, 0, 0);
}

// ---- weight split into swizzled B layout [K/32][N][32] ----
template<int TRANS>   // TRANS=1: W is [K][N]; TRANS=0: W is [N][K]
__global__ void wsplit_k(const float* __restrict__ W, u16* __restrict__ hi,
                         u16* __restrict__ lo, int K, int N) {
    int gid = blockIdx.x * 256 + threadIdx.x;
    int total = (K >> 5) * N * 4;
    if (gid >= total) return;
    int g = gid & 3, n = (gid >> 2) % N, kc = gid / (4 * N);
    float v[8];
#pragma unroll
    for (int e = 0; e < 8; e++) {
        int k = kc * 32 + g * 8 + e;
        v[e] = TRANS ? W[(size_t)k * N + n] : W[(size_t)n * K + k];
    }
    uint4 H, L;
    pack8(v, H, L);
    int p = g ^ ((n >> 1) & 3);
    size_t off = ((size_t)kc * N + n) * 32 + p * 8;
    *(uint4*)(hi + off) = H;
    *(uint4*)(lo + off) = L;
}

// ---------------- split-bf16 MFMA GEMM ----------------
// C[M x 128*gridz] = (sum_p A_p)[M x K] * B[N x K], B swizzled [K/32][N][32].
// Single-buffered A tile, double-buffered B via global_load_lds. 2 blocks/CU.
template<int BM, int GMODE, int NPART, int BIASA, int SPLITOUT, int BIASC, int DUAL>
__global__ __launch_bounds__(512, 4) void gemm3_k(
    const float* __restrict__ A, int ldA, int Mtot,
    const u16* __restrict__ Bhi, const u16* __restrict__ Blo,
    const u16* __restrict__ Bhi2, const u16* __restrict__ Blo2, int Nfull,
    float* __restrict__ C, int ldC, long partStride,
    u16* __restrict__ Chi, u16* __restrict__ Clo, int Nout,
    const float* __restrict__ biasA,
    const float* __restrict__ biasC, const float* __restrict__ biasC2,
    const int* __restrict__ tok, int kchunk, int Mhalf)
{
    constexpr int BN = 128;
    constexpr int WROWS = BM / 64;          // waves along M
    constexpr int WCOLS = 8 / WROWS;        // waves along N
    constexpr int WTN = BN / WCOLS;         // wave-tile N width
    constexpr int NT = WTN / 16;            // 16-col tiles per wave
    constexpr int AF = BM / 16;             // A floats per thread
    constexpr int TPR = 512 / BM;           // threads per A row
    constexpr int NG = AF / 8;              // granules per thread

    const int t = threadIdx.x;
    const int lane = t & 63, wv = t >> 6;
    const int fm = lane & 15, fq = lane >> 4;
    const int wm0 = (wv / WCOLS) * 64;
    const int wn0 = (wv % WCOLS) * WTN;
    const int m0 = blockIdx.x * BM;
    const int n0 = blockIdx.z * BN;
    const int kbeg = blockIdx.y * kchunk;

    __shared__ alignas(16) u16 sAhi[BM * 32];
    __shared__ alignas(16) u16 sAlo[BM * 32];
    __shared__ alignas(16) u16 sBhi[2][BN * 32];
    __shared__ alignas(16) u16 sBlo[2][BN * 32];
    __shared__ int sRow[BM];

    if (t < BM) {
        int r;
        if (GMODE == 0) r = m0 + t;
        else if (GMODE == 1) r = tok[m0 + t];
        else {
            int trip = m0 + t;
            int rem = trip & (Mhalf - 1);
            int l = rem >> 6, b = rem & 63;
            r = (trip < Mhalf) ? (b * 64 + l) : (b * 64 + (63 - l));
        }
        sRow[t] = r;
    }
    __syncthreads();

    const bool second = DUAL && (m0 >= Mhalf);
    const u16* __restrict__ bhp = second ? Bhi2 : Bhi;
    const u16* __restrict__ blp = second ? Blo2 : Blo;

    // A staging: thread owns row r, AF cols starting at co
    const int r = t / TPR, q = t % TPR, co = q * AF;
    const int sw = (r >> 1) & 3;
    const float* Abase = A + (size_t)sRow[r] * ldA + co;
    const size_t pstep = (size_t)Mtot * ldA;

    // B DMA (chunk-contiguous)
    const size_t bstep = (size_t)Nfull * 32;
    const u16* gbh = bhp + ((size_t)(kbeg >> 5) * Nfull + n0) * 32 + t * 8;
    const u16* gbl = blp + ((size_t)(kbeg >> 5) * Nfull + n0) * 32 + t * 8;

    f32x4 acc[4][NT];
#pragma unroll
    for (int i = 0; i < 4; i++)
#pragma unroll
        for (int j = 0; j < NT; j++) acc[i][j] = (f32x4){0.f, 0.f, 0.f, 0.f};

    float av[AF];
    auto loadA = [&](int kk) {
#pragma unroll
        for (int c = 0; c < AF; c += 4) {
            float4 s = *(const float4*)(Abase + kk + c);
            av[c] = s.x; av[c + 1] = s.y; av[c + 2] = s.z; av[c + 3] = s.w;
        }
#pragma unroll
        for (int p = 1; p < NPART; p++) {
#pragma unroll
            for (int c = 0; c < AF; c += 4) {
                float4 s = *(const float4*)(Abase + (size_t)p * pstep + kk + c);
                av[c] += s.x; av[c + 1] += s.y; av[c + 2] += s.z; av[c + 3] += s.w;
            }
        }
        if (BIASA) {
#pragma unroll
            for (int c = 0; c < AF; c += 4) {
                float4 s = *(const float4*)(biasA + kk + co + c);
                av[c] += s.x; av[c + 1] += s.y; av[c + 2] += s.z; av[c + 3] += s.w;
            }
        }
    };
    auto storeA = [&]() {
#pragma unroll
        for (int g = 0; g < NG; g++) {
            uint4 H, L;
            pack8t(av + 8 * g, H, L);
            int p = ((co >> 3) + g) ^ sw;
            *(uint4*)&sAhi[r * 32 + p * 8] = H;
            *(uint4*)&sAlo[r * 32 + p * 8] = L;
        }
    };
    const int pf8 = (fq ^ ((fm >> 1) & 3)) * 8;
    auto compute = [&](int cur) {
        bf16x8 bh4[NT], bl4[NT];
#pragma unroll
        for (int j = 0; j < NT; j++) {
            int off = (wn0 + 16 * j + fm) * 32 + pf8;
            bh4[j] = *(const bf16x8*)&sBhi[cur][off];
            bl4[j] = *(const bf16x8*)&sBlo[cur][off];
        }
#pragma unroll
        for (int i = 0; i < 4; i++) {
            int off = (wm0 + 16 * i + fm) * 32 + pf8;
            bf16x8 ah = *(const bf16x8*)&sAhi[off];
            bf16x8 al = *(const bf16x8*)&sAlo[off];
#pragma unroll
            for (int j = 0; j < NT; j++) {
                acc[i][j] = __builtin_amdgcn_mfma_f32_16x16x32_bf16(ah, bh4[j], acc[i][j], 0, 0, 0);
                acc[i][j] = __builtin_amdgcn_mfma_f32_16x16x32_bf16(ah, bl4[j], acc[i][j], 0, 0, 0);
                acc[i][j] = __builtin_amdgcn_mfma_f32_16x16x32_bf16(al, bh4[j], acc[i][j], 0, 0, 0);
            }
        }
    };

    const int iters = kchunk >> 5;
    // prologue
    loadA(kbeg);
    glds16(gbh, &sBhi[0][wv * 512]);
    glds16(gbl, &sBlo[0][wv * 512]);
    storeA();
    __syncthreads();

#pragma unroll 1
    for (int k = 0; k < iters; k++) {
        const int cur = k & 1;
        const bool pf = (k + 1 < iters);
        if (pf) {
            glds16(gbh + (size_t)(k + 1) * bstep, &sBhi[cur ^ 1][wv * 512]);
            glds16(gbl + (size_t)(k + 1) * bstep, &sBlo[cur ^ 1][wv * 512]);
        }
        compute(cur);
        __syncthreads();                  // readers done with sA(k); DMA drained
        if (pf) {
            loadA(kbeg + (k + 1) * 32);   // latency covered by co-resident block
            storeA();
        }
        __syncthreads();
    }

    if (!SPLITOUT) {
        float* Cp = C + (size_t)blockIdx.y * partStride;
        const float* bc = second ? biasC2 : biasC;
#pragma unroll
        for (int i = 0; i < 4; i++)
#pragma unroll
            for (int j = 0; j < NT; j++)
#pragma unroll
                for (int rr = 0; rr < 4; rr++) {
                    int row = m0 + wm0 + 16 * i + fq * 4 + rr;
                    int col = n0 + wn0 + 16 * j + fm;
                    float v = acc[i][j][rr];
                    if (BIASC) v += bc[col];
                    Cp[(size_t)row * ldC + col] = v;
                }
    } else {
        // BM==256 only: C tile rows become swizzled B-layout k-chunks
        float* scr = (float*)&sAhi[0];     // 32 x 128 fp32 = 16 KB
        const int kc0 = m0 >> 5;
        const int n = t & 127, gs = t >> 7;
        const int ngl = n0 + n;
        const int pp = gs ^ ((ngl >> 1) & 3);
#pragma unroll 1
        for (int g8 = 0; g8 < BM / 32; g8++) {
            if ((wv >> 1) == (g8 >> 1)) {
                int ib = (g8 & 1) * 2;
#pragma unroll
                for (int i2 = 0; i2 < 2; i2++)
#pragma unroll
                    for (int j = 0; j < NT; j++)
#pragma unroll
                        for (int rr = 0; rr < 4; rr++)
                            scr[(i2 * 16 + fq * 4 + rr) * BN + wn0 + 16 * j + fm] =
                                acc[ib + i2][j][rr];
            }
            __syncthreads();
            float v[8];
#pragma unroll
            for (int e = 0; e < 8; e++) v[e] = scr[(gs * 8 + e) * BN + n];
            uint4 H, L;
            pack8(v, H, L);
            size_t off = ((size_t)(kc0 + g8) * Nout + ngl) * 32 + pp * 8;
            *(uint4*)(Chi + off) = H;
            *(uint4*)(Clo + off) = L;
            __syncthreads();
        }
    }
}

// ---------------- BiLSTM ----------------
__device__ __forceinline__ float rl(float v, int l) {
    return __builtin_bit_cast(float, __builtin_amdgcn_readlane(__builtin_bit_cast(int, v), l));
}
__device__ __forceinline__ float fsigmoid(float x) { return 1.f / (1.f + __expf(-x)); }
__device__ __forceinline__ float ftanh(float x) {
    float e = __expf(2.f * x);
    return 1.f - 2.f / (e + 1.f);
}

__global__ __launch_bounds__(512, 2) void lstm_k(
    const float* __restrict__ xp,       // [2][64(l)][64(b)][512]
    const float* __restrict__ Whh_f, const float* __restrict__ Whh_b,
    const int* __restrict__ lengths,
    float* __restrict__ hfin)           // [2][64][128]
{
    const int bid = blockIdx.x;
    const int dir = bid >> 6;
    const int b = bid & 63;
    const int t = threadIdx.x;
    const int lane = t & 63, wv = t >> 6;
    const int gtype = wv >> 1;
    const float* Whh = dir ? Whh_b : Whh_f;
    const int len = lengths[b];

    float wr[128];
#pragma unroll
    for (int i = 0; i < 128; i += 4) {
        float4 v = *(const float4*)(Whh + t * 128 + i);
        wr[i] = v.x; wr[i + 1] = v.y; wr[i + 2] = v.z; wr[i + 3] = v.w;
    }

    __shared__ float gact[2][512];
    float h0 = 0.f, h1 = 0.f, c0 = 0.f, c1 = 0.f;
    const float* xpp = xp + ((size_t)dir * 4096 + b) * 512 + t;

    for (int l = 0; l < 64; l++) {
        float xg = xpp[(size_t)l * 32768];
        float a0 = xg, a1 = 0.f, a2 = 0.f, a3 = 0.f;
#pragma unroll
        for (int j = 0; j < 64; j += 2) {
            a0 = fmaf(wr[j], rl(h0, j), a0);
            a1 = fmaf(wr[j + 1], rl(h0, j + 1), a1);
        }
#pragma unroll
        for (int j = 0; j < 64; j += 2) {
            a2 = fmaf(wr[64 + j], rl(h1, j), a2);
            a3 = fmaf(wr[64 + j + 1], rl(h1, j + 1), a3);
        }
        float acc = (a0 + a1) + (a2 + a3);
        float act = (gtype == 2) ? ftanh(acc) : fsigmoid(acc);
        gact[l & 1][t] = act;
        __syncthreads();
        float iv0 = gact[l & 1][lane],       iv1 = gact[l & 1][64 + lane];
        float fv0 = gact[l & 1][128 + lane], fv1 = gact[l & 1][192 + lane];
        float gv0 = gact[l & 1][256 + lane], gv1 = gact[l & 1][320 + lane];
        float ov0 = gact[l & 1][384 + lane], ov1 = gact[l & 1][448 + lane];
        float cn0 = fv0 * c0 + iv0 * gv0;
        float cn1 = fv1 * c1 + iv1 * gv1;
        float hn0 = ov0 * ftanh(cn0);
        float hn1 = ov1 * ftanh(cn1);
        bool upd = ((dir == 0) ? l : (63 - l)) < len;
        if (upd) { c0 = cn0; c1 = cn1; h0 = hn0; h1 = hn1; }
    }
    if (wv == 0) {
        hfin[((size_t)dir * 64 + b) * 128 + lane] = h0;
        hfin[((size_t)dir * 64 + b) * 128 + 64 + lane] = h1;
    }
}

__global__ void fc_k(const float* __restrict__ hf, const float* __restrict__ Wfc,
                     const float* __restrict__ bfc, float* __restrict__ out) {
    int t = threadIdx.x;
    int b = t >> 2, c = t & 3;
    float s = bfc[c];
#pragma unroll 4
    for (int j = 0; j < 128; j++) s = fmaf(hf[b * 128 + j], Wfc[c * 256 + j], s);
#pragma unroll 4
    for (int j = 0; j < 128; j++) s = fmaf(hf[(64 + b) * 128 + j], Wfc[c * 256 + 128 + j], s);
    out[b * 4 + c] = s;
}

extern "C" void kernel_launch(void* const* d_in, const int* in_sizes, int n_in,
                              void* d_out, int out_size, void* d_ws, size_t ws_size,
                              hipStream_t stream) {
    const float* A     = (const float*)d_in[0];
    const float* X     = (const float*)d_in[1];
    const int*   tok   = (const int*)d_in[2];
    const int*   lens  = (const int*)d_in[3];
    const float* W1    = (const float*)d_in[4];
    const float* b1    = (const float*)d_in[5];
    const float* W2    = (const float*)d_in[6];
    const float* b2    = (const float*)d_in[7];
    const float* Wih_f = (const float*)d_in[8];
    const float* Whh_f = (const float*)d_in[9];
    const float* b_f   = (const float*)d_in[10];
    const float* Wih_b = (const float*)d_in[11];
    const float* Whh_b = (const float*)d_in[12];
    const float* b_b   = (const float*)d_in[13];
    const float* Wfc   = (const float*)d_in[14];
    const float* bfc   = (const float*)d_in[15];
    float* out = (float*)d_out;
    char* ws = (char*)d_ws;

    // workspace map (bytes) — region0 reused: H1p (K2->K3), then sqP + xp
    float* H1p  = (float*)(ws + 0);              // [8][8192][256] = 64 MB
    float* sqP  = (float*)(ws + 0);              // [16][4096][128] = 32 MB
    float* xp   = (float*)(ws + 33554432);       // [2][64][64][512] = 16 MB
    u16*   B1hi = (u16*)(ws + 67108864);         // [256][256][32] = 4 MB
    u16*   B1lo = (u16*)(ws + 71303168);
    u16*   B2hi = (u16*)(ws + 75497472);         // [256][128][32] = 2 MB
    u16*   B2lo = (u16*)(ws + 77594624);
    float* hfin = (float*)(ws + 79691776);       // 64 KB
    u16*   W1h  = (u16*)(ws + 79757312);         // 128 KB
    u16*   W1l  = (u16*)(ws + 79888384);
    u16*   W2h  = (u16*)(ws + 80019456);         // 64 KB
    u16*   W2l  = (u16*)(ws + 80084992);
    u16*   Wfh  = (u16*)(ws + 80150528);         // 128 KB
    u16*   Wfl  = (u16*)(ws + 80281600);
    u16*   Wbh  = (u16*)(ws + 80412672);
    u16*   Wbl  = (u16*)(ws + 80543744);

    wsplit_k<1><<<32, 256, 0, stream>>>(W1, W1h, W1l, 256, 256);
    wsplit_k<1><<<16, 256, 0, stream>>>(W2, W2h, W2l, 256, 128);
    wsplit_k<0><<<32, 256, 0, stream>>>(Wih_f, Wfh, Wfl, 128, 512);
    wsplit_k<0><<<32, 256, 0, stream>>>(Wih_b, Wbh, Wbl, 128, 512);

    // K1: B1 = swizzle_split(X @ W1)   grid (32 m, 1, 2 n)
    gemm3_k<256, 0, 1, 0, 1, 0, 0><<<dim3(32, 1, 2), 512, 0, stream>>>(
        X, 256, 8192, W1h, W1l, nullptr, nullptr, 256,
        nullptr, 0, 0, B1hi, B1lo, 256,
        nullptr, nullptr, nullptr, nullptr, 256, 4096);
    // K2: H1p[s] = A @ B1 (split-K 8)  grid (32 m, 8 k, 2 n) = 512 blocks
    gemm3_k<256, 0, 1, 0, 0, 0, 0><<<dim3(32, 8, 2), 512, 0, stream>>>(
        A, 8192, 8192, B1hi, B1lo, nullptr, nullptr, 256,
        H1p, 256, (long)8192 * 256, nullptr, nullptr, 0,
        nullptr, nullptr, nullptr, nullptr, 1024, 4096);
    // K3: B2 = swizzle_split((sum8 H1p + b1) @ W2)   grid (32, 1, 1)
    gemm3_k<256, 0, 8, 1, 1, 0, 0><<<dim3(32, 1, 1), 512, 0, stream>>>(
        H1p, 256, 8192, W2h, W2l, nullptr, nullptr, 128,
        nullptr, 0, 0, B2hi, B2lo, 128,
        b1, nullptr, nullptr, nullptr, 256, 4096);
    // K4: sqP[s] = A[tok] @ B2 (split-K 16)   grid (16 m, 16 k, 1)
    gemm3_k<256, 1, 1, 0, 0, 0, 0><<<dim3(16, 16, 1), 512, 0, stream>>>(
        A, 8192, 8192, B2hi, B2lo, nullptr, nullptr, 128,
        sqP, 128, (long)4096 * 128, nullptr, nullptr, 0,
        nullptr, nullptr, nullptr, tok, 512, 4096);
    // K5: xp = (sum16 sqP + b2)[trip] @ Wih^T + b   grid (64 m, 1, 4 n)
    gemm3_k<128, 2, 16, 1, 0, 1, 1><<<dim3(64, 1, 4), 512, 0, stream>>>(
        sqP, 128, 4096, Wfh, Wfl, Wbh, Wbl, 512,
        xp, 512, 0, nullptr, nullptr, 0,
        b2, b_f, b_b, nullptr, 128, 4096);
    // K6: BiLSTM
    lstm_k<<<128, 512, 0, stream>>>(xp, Whh_f, Whh_b, lens, hfin);
    // K7: final FC
    fc_k<<<1, 256, 0, stream>>>(hfin, Wfc, bfc, out);
}